// Round 1
// baseline (308.170 us; speedup 1.0000x reference)
//
#include <hip/hip_runtime.h>
#include <hip/hip_bf16.h>

#define BB 8
#define CC 64
#define LL 2048
#define LH 1024
#define HH 8
#define EE 8

// ---------------- helpers ----------------
__device__ inline float wave_red_sum(float v) {
#pragma unroll
    for (int off = 32; off > 0; off >>= 1) v += __shfl_down(v, off, 64);
    return v;
}

// ---------------- k0: zero the stat accumulators ----------------
__global__ void k0_zero(float* stats) {
    stats[threadIdx.x] = 0.f;   // 512 threads, 512 floats
}

// ---------------- k1: q conv -> sigmoid gate -> k conv ----------------
// grid (L/256, B, G), block 256
__global__ void k1_gate(const float* __restrict__ x, const float* __restrict__ q_w,
                        const float* __restrict__ k_w,
                        float* __restrict__ x_atten, float* __restrict__ q_) {
    int l = blockIdx.x * 256 + threadIdx.x;
    int b = blockIdx.y, g = blockIdx.z;
    __shared__ float wq[256], wk[256];
    wq[threadIdx.x] = q_w[g * 256 + threadIdx.x];
    wk[threadIdx.x] = k_w[g * 256 + threadIdx.x];
    __syncthreads();
    const float* xb = x + (b * CC + g * 16) * LL + l;
    float* xab = x_atten + (b * CC + g * 16) * LL + l;
    float* qb  = q_      + (b * CC + g * 16) * LL + l;
    float xv[16], xat[16];
#pragma unroll
    for (int ic = 0; ic < 16; ++ic) xv[ic] = xb[ic * LL];
#pragma unroll
    for (int oc = 0; oc < 16; ++oc) {
        float acc = 0.f;
#pragma unroll
        for (int ic = 0; ic < 16; ++ic) acc = fmaf(wq[oc * 16 + ic], xv[ic], acc);
        float sg = 1.f / (1.f + __expf(-acc));
        xat[oc] = xv[oc] * sg;
        xab[oc * LL] = xat[oc];
    }
#pragma unroll
    for (int oc = 0; oc < 16; ++oc) {
        float acc = 0.f;
#pragma unroll
        for (int ic = 0; ic < 16; ++ic) acc = fmaf(wk[oc * 16 + ic], xat[ic], acc);
        qb[oc * LL] = acc;
    }
}

// ---------------- k2: down conv (groups=2, K=3) on odd/even concat + BN1 stats ----------------
// grid (LH/256, 64, B), block 256. One oc per block.
__global__ void k2_down(const float* __restrict__ x_atten, const float* __restrict__ down_w,
                        float* __restrict__ xa_conv, float* __restrict__ bsum, float* __restrict__ bsumsq) {
    int t = blockIdx.x * 256 + threadIdx.x;
    int oc = blockIdx.y, b = blockIdx.z;
    __shared__ float w[192];
    __shared__ float red[8];
    if (threadIdx.x < 192) w[threadIdx.x] = down_w[oc * 192 + threadIdx.x];
    __syncthreads();
    // group 0 (oc<32): odd positions; group 1: even positions
    int po = (oc < 32) ? 1 : 0;
    const float* src = x_atten + b * CC * LL;
    int p0 = 2 * t + po;
    bool hm = (t > 0), hp = (t < LH - 1);
    float acc = 0.f;
#pragma unroll 8
    for (int ic = 0; ic < 64; ++ic) {
        const float* s = src + ic * LL;
        float xm = hm ? s[p0 - 2] : 0.f;
        float x0 = s[p0];
        float xp = hp ? s[p0 + 2] : 0.f;
        acc = fmaf(w[ic * 3 + 0], xm, acc);
        acc = fmaf(w[ic * 3 + 1], x0, acc);
        acc = fmaf(w[ic * 3 + 2], xp, acc);
    }
    xa_conv[(b * CC + oc) * LH + t] = acc;
    float s1 = wave_red_sum(acc);
    float s2 = wave_red_sum(acc * acc);
    int wid = threadIdx.x >> 6, lane = threadIdx.x & 63;
    if (lane == 0) { red[wid] = s1; red[4 + wid] = s2; }
    __syncthreads();
    if (threadIdx.x == 0) {
        atomicAdd(&bsum[oc],   red[0] + red[1] + red[2] + red[3]);
        atomicAdd(&bsumsq[oc], red[4] + red[5] + red[6] + red[7]);
    }
}

// ---------------- k3: BN finalize (shared by BN1/BN2) ----------------
__global__ void k3_bnfin(const float* __restrict__ bsum, const float* __restrict__ bsumsq,
                         const float* __restrict__ gamma, const float* __restrict__ beta,
                         float* __restrict__ scale, float* __restrict__ shift, float invN) {
    int c = threadIdx.x;  // 64
    float m = bsum[c] * invN;
    float var = bsumsq[c] * invN - m * m;
    float rstd = rsqrtf(var + 1e-5f);
    float sc = gamma[c] * rstd;
    scale[c] = sc;
    shift[c] = beta[c] - m * sc;
}

// ---------------- k4: BN1 apply + relu + v/v1 grouped 1x1 convs ----------------
// grid (B*LH/256, G), block 256
__global__ void k4_vv(const float* __restrict__ xa_conv, const float* __restrict__ v_w,
                      const float* __restrict__ v1_w, const float* __restrict__ scale,
                      const float* __restrict__ shift,
                      float* __restrict__ v, float* __restrict__ v1) {
    int idx = blockIdx.x * 256 + threadIdx.x;
    int b = idx >> 10, t = idx & (LH - 1);
    int g = blockIdx.y;
    __shared__ float wv[256], wv1[256], sc[16], sh[16];
    wv[threadIdx.x]  = v_w[g * 256 + threadIdx.x];
    wv1[threadIdx.x] = v1_w[g * 256 + threadIdx.x];
    if (threadIdx.x < 16) {
        sc[threadIdx.x] = scale[g * 16 + threadIdx.x];
        sh[threadIdx.x] = shift[g * 16 + threadIdx.x];
    }
    __syncthreads();
    float xv[16];
#pragma unroll
    for (int ic = 0; ic < 16; ++ic) {
        float raw = xa_conv[(b * CC + g * 16 + ic) * LH + t];
        xv[ic] = fmaxf(fmaf(raw, sc[ic], sh[ic]), 0.f);
    }
#pragma unroll
    for (int oc = 0; oc < 16; ++oc) {
        float a0 = 0.f, a1 = 0.f;
#pragma unroll
        for (int ic = 0; ic < 16; ++ic) {
            a0 = fmaf(wv[oc * 16 + ic], xv[ic], a0);
            a1 = fmaf(wv1[oc * 16 + ic], xv[ic], a1);
        }
        v [(b * CC + g * 16 + oc) * LH + t] = a0;
        v1[(b * CC + g * 16 + oc) * LH + t] = a1;
    }
}

// ---------------- k5: attention per (b,h) + residual ----------------
// grid (L/256, H, B), block 256
__global__ void __launch_bounds__(256, 1) k5_attn(
        const float* __restrict__ q_, const float* __restrict__ v,
        const float* __restrict__ v1, const float* __restrict__ x_atten,
        float* __restrict__ attn_out, float* __restrict__ xs) {
    __shared__ float Kl[EE][LH];
    __shared__ float Vl[EE][LH];
    int b = blockIdx.z, h = blockIdx.y;
    int l = blockIdx.x * 256 + threadIdx.x;
    const float* kb = v  + (b * CC + h * EE) * LH;
    const float* vb = v1 + (b * CC + h * EE) * LH;
    for (int i = threadIdx.x; i < EE * LH; i += 256) {
        Kl[i >> 10][i & (LH - 1)] = kb[i];
        Vl[i >> 10][i & (LH - 1)] = vb[i];
    }
    __syncthreads();
    const float rs = 0.35355339059327373f;  // 1/sqrt(8)
    float qv[EE];
#pragma unroll
    for (int e = 0; e < EE; ++e) qv[e] = q_[(b * CC + h * EE + e) * LL + l] * rs;
    float mrun = -1e30f, lrun = 0.f;
    float oacc[EE];
#pragma unroll
    for (int e = 0; e < EE; ++e) oacc[e] = 0.f;
    for (int m0 = 0; m0 < LH; m0 += 32) {
        float s[32];
#pragma unroll
        for (int j = 0; j < 32; ++j) {
            int m = m0 + j;
            float a = qv[0] * Kl[0][m];
#pragma unroll
            for (int e = 1; e < EE; ++e) a = fmaf(qv[e], Kl[e][m], a);
            s[j] = a;
        }
        float cm = s[0];
#pragma unroll
        for (int j = 1; j < 32; ++j) cm = fmaxf(cm, s[j]);
        float nm = fmaxf(mrun, cm);
        float corr = __expf(mrun - nm);
        lrun *= corr;
#pragma unroll
        for (int e = 0; e < EE; ++e) oacc[e] *= corr;
        mrun = nm;
#pragma unroll
        for (int j = 0; j < 32; ++j) {
            float p = __expf(s[j] - nm);
            lrun += p;
            int m = m0 + j;
#pragma unroll
            for (int e = 0; e < EE; ++e) oacc[e] = fmaf(p, Vl[e][m], oacc[e]);
        }
    }
    float inv = 1.f / lrun;
#pragma unroll
    for (int e = 0; e < EE; ++e) {
        int gi = (b * CC + h * EE + e) * LL + l;
        float o = oacc[e] * inv;
        attn_out[gi] = o;
        xs[gi] = o + x_atten[gi];
    }
}

// ---------------- k6: out conv (groups=4, K=3) over concat(xs,q_,out) + residual + BN2 stats ----------------
// grid (L/256, 64, B), block 256
__global__ void k6_outconv(const float* __restrict__ xs, const float* __restrict__ q_,
                           const float* __restrict__ attn_out, const float* __restrict__ out_w,
                           float* __restrict__ preBN, float* __restrict__ bsum, float* __restrict__ bsumsq) {
    int t = blockIdx.x * 256 + threadIdx.x;
    int oc = blockIdx.y, b = blockIdx.z;
    __shared__ float w[144];
    __shared__ float red[8];
    if (threadIdx.x < 144) w[threadIdx.x] = out_w[oc * 144 + threadIdx.x];
    __syncthreads();
    int g = oc >> 4;
    bool hm = (t > 0), hp = (t < LL - 1);
    float acc = 0.f;
#pragma unroll 4
    for (int ic = 0; ic < 48; ++ic) {
        int jc = g * 48 + ic;
        const float* s;
        if (jc < 64)       s = xs       + (b * CC + jc)       * LL;
        else if (jc < 128) s = q_       + (b * CC + jc - 64)  * LL;
        else               s = attn_out + (b * CC + jc - 128) * LL;
        float xm = hm ? s[t - 1] : 0.f;
        float x0 = s[t];
        float xp = hp ? s[t + 1] : 0.f;
        acc = fmaf(w[ic * 3 + 0], xm, acc);
        acc = fmaf(w[ic * 3 + 1], x0, acc);
        acc = fmaf(w[ic * 3 + 2], xp, acc);
    }
    float val = acc + xs[(b * CC + oc) * LL + t];
    preBN[(b * CC + oc) * LL + t] = val;
    float s1 = wave_red_sum(val);
    float s2 = wave_red_sum(val * val);
    int wid = threadIdx.x >> 6, lane = threadIdx.x & 63;
    if (lane == 0) { red[wid] = s1; red[4 + wid] = s2; }
    __syncthreads();
    if (threadIdx.x == 0) {
        atomicAdd(&bsum[oc],   red[0] + red[1] + red[2] + red[3]);
        atomicAdd(&bsumsq[oc], red[4] + red[5] + red[6] + red[7]);
    }
}

// ---------------- k8: BN2 apply + relu -> out ----------------
// grid over 1M/4 elems, block 256
__global__ void k8_apply(const float* __restrict__ preBN, const float* __restrict__ scale,
                         const float* __restrict__ shift, float* __restrict__ outp) {
    int i = blockIdx.x * 256 + threadIdx.x;  // float4 index, 262144 total
    float4 vv = reinterpret_cast<const float4*>(preBN)[i];
    int c = (i >> 9) & 63;
    float sc = scale[c], sh = shift[c];
    float4 r;
    r.x = fmaxf(fmaf(vv.x, sc, sh), 0.f);
    r.y = fmaxf(fmaf(vv.y, sc, sh), 0.f);
    r.z = fmaxf(fmaf(vv.z, sc, sh), 0.f);
    r.w = fmaxf(fmaf(vv.w, sc, sh), 0.f);
    reinterpret_cast<float4*>(outp)[i] = r;
}

extern "C" void kernel_launch(void* const* d_in, const int* in_sizes, int n_in,
                              void* d_out, int out_size, void* d_ws, size_t ws_size,
                              hipStream_t stream) {
    const float* x          = (const float*)d_in[0];
    const float* q_w        = (const float*)d_in[1];
    const float* k_w        = (const float*)d_in[2];
    const float* v_w        = (const float*)d_in[3];
    const float* v1_w       = (const float*)d_in[4];
    const float* out_w      = (const float*)d_in[5];
    const float* down_w     = (const float*)d_in[6];
    const float* down_gamma = (const float*)d_in[7];
    const float* down_beta  = (const float*)d_in[8];
    const float* gamma      = (const float*)d_in[9];
    const float* beta       = (const float*)d_in[10];
    float* outp = (float*)d_out;

    float* ws = (float*)d_ws;
    float* x_atten  = ws;                 // 1048576
    float* q_s      = ws + 1048576;       // 1048576
    float* xa_conv  = ws + 2097152;       // 524288
    float* vbuf     = ws + 2621440;       // 524288
    float* v1buf    = ws + 3145728;       // 524288
    float* attn_out = ws + 3670016;       // 1048576
    float* xsbuf    = ws + 4718592;       // 1048576
    float* preBN    = ws + 5767168;       // 1048576
    float* stats    = ws + 6815744;       // 512 floats
    // stats layout: [0]sum1 [64]sumsq1 [128]scale1 [192]shift1 [256]sum2 [320]sumsq2 [384]scale2 [448]shift2

    k0_zero<<<1, 512, 0, stream>>>(stats);
    k1_gate<<<dim3(LL / 256, BB, 4), 256, 0, stream>>>(x, q_w, k_w, x_atten, q_s);
    k2_down<<<dim3(LH / 256, CC, BB), 256, 0, stream>>>(x_atten, down_w, xa_conv,
                                                        stats + 0, stats + 64);
    k3_bnfin<<<1, 64, 0, stream>>>(stats + 0, stats + 64, down_gamma, down_beta,
                                   stats + 128, stats + 192, 1.f / (BB * LH));
    k4_vv<<<dim3(BB * LH / 256, 4), 256, 0, stream>>>(xa_conv, v_w, v1_w,
                                                      stats + 128, stats + 192, vbuf, v1buf);
    k5_attn<<<dim3(LL / 256, HH, BB), 256, 0, stream>>>(q_s, vbuf, v1buf, x_atten,
                                                        attn_out, xsbuf);
    k6_outconv<<<dim3(LL / 256, CC, BB), 256, 0, stream>>>(xsbuf, q_s, attn_out, out_w,
                                                           preBN, stats + 256, stats + 320);
    k3_bnfin<<<1, 64, 0, stream>>>(stats + 256, stats + 320, gamma, beta,
                                   stats + 384, stats + 448, 1.f / (BB * LL));
    k8_apply<<<dim3((BB * CC * LL / 4) / 256), 256, 0, stream>>>(preBN, stats + 384,
                                                                 stats + 448, outp);
}